// Round 10
// baseline (119.436 us; speedup 1.0000x reference)
//
#include <hip/hip_runtime.h>

// Problem constants (match reference): B=64, L=2048, H=256, K=32
#define LL 2048
#define BB 64
#define HH 256
#define KK 32

#define NB  1024   // 4 blocks/CU exactly (LDS 33.5 KB/block)
#define WPB 4      // waves per block

typedef __attribute__((ext_vector_type(8))) short  short8;   // 8 bf16 (4 VGPRs)
typedef __attribute__((ext_vector_type(4))) float  f32x4;

__device__ __forceinline__ float softplus_f(float x) {
    return x > 20.f ? x : __logf(1.f + __expf(x));
}
// round-to-nearest-even fp32 -> bf16
__device__ __forceinline__ unsigned f2bf(float x) {
    unsigned u = __builtin_bit_cast(unsigned, x);
    return (u + 0x7FFFu + ((u >> 16) & 1u)) >> 16;
}
__device__ __forceinline__ float bfhi(unsigned u) {   // high bf16 -> f32
    return __builtin_bit_cast(float, u & 0xFFFF0000u);
}
__device__ __forceinline__ float bflo(unsigned u) {   // low bf16 -> f32
    return __builtin_bit_cast(float, u << 16);
}

struct RowT { float4 h, c, t, o, d; };

// 8 flat rows per wave-tile. Per-wave LDS A-tile = 8 v-rows (4 KB, swizzled).
// term 1 (hidden dot at single column e) computed INLINE during staging via
// register butterfly - hidden never touches LDS. 3-deep load rotation keeps
// ~6 KB/wave of global reads in flight. MFMA C rows 0-7 = v-dots (term 2).
__global__ __launch_bounds__(256, 4) void nhll_main(
    const int*   __restrict__ events,   // [B, L]
    const int*   __restrict__ lens,     // [B]
    const float* __restrict__ ttime,    // [B]
    const float* __restrict__ hidden,   // [L, B, H]
    const float* __restrict__ cell,     // [L, B, H]
    const float* __restrict__ ctarg,    // [L, B, H]
    const float* __restrict__ outp,     // [L, B, H]
    const float* __restrict__ decay,    // [L, B, H]
    const float* __restrict__ simt,     // [L, B]
    const float* __restrict__ W,        // [H, K]
    const float* __restrict__ bias,     // [K]
    float*       __restrict__ partial)  // [NB]
{
    __shared__ __align__(16) char  WTs[KK * HH * 2];       // 16 KB W^T bf16, swizzled
    __shared__ __align__(16) char  Als[WPB][8 * HH * 2];   // 4 KB per wave (v-rows)
    __shared__ int   pfx[BB + 1];
    __shared__ float coef_s[BB];
    __shared__ float wacc[WPB];

    const int tid  = threadIdx.x;
    const int lane = tid & 63;
    const int q    = tid >> 6;
    const int g    = lane >> 4;     // h-octet within K-chunk
    const int m    = lane & 15;     // C-col index

    // ---- one-time: W^T bf16 into LDS (row k, position h=tid, swizzled) ----
    {
        const float* wrow = &W[tid * KK];
#pragma unroll
        for (int k = 0; k < KK; ++k) {
            const int byte = (k * 512 + tid * 2) ^ ((k & 7) << 4);
            *(unsigned short*)(WTs + byte) = (unsigned short)f2bf(wrow[k]);
        }
    }
    if (tid < BB) {                 // wave 0: scan lens -> prefix sums
        const int ln = lens[tid];
        coef_s[tid] = ttime[tid] / (float)ln;
        int s = ln;
#pragma unroll
        for (int mm = 1; mm < 64; mm <<= 1) {
            const int t = __shfl_up(s, mm, 64);
            if (lane >= mm) s += t;
        }
        pfx[tid + 1] = s;
        if (tid == 0) pfx[0] = 0;
    }
    __syncthreads();

    const float b_lo = bias[m];
    const float b_hi = bias[16 + m];
    const int   T      = pfx[BB];
    const int   ntiles = (T + 7) >> 3;
    char* Aw = Als[q];
    float acc = 0.f;

    for (int tile = blockIdx.x * WPB + q; tile < ntiles; tile += NB * WPB) {
        // ---- parallel metadata: lane j (j = lane&7) owns flat row tile*8+j ----
        int i = tile * 8 + (lane & 7);
        const int valid = (i < T) ? 1 : 0;
        if (!valid) i = T - 1;                    // clamp; masked below
        int lo = 0, hi = BB;
#pragma unroll
        for (int s = 0; s < 6; ++s) {
            const int mid = (lo + hi) >> 1;
            if (pfx[mid] <= i) lo = mid; else hi = mid;
        }
        const int   b    = lo;
        const int   l    = i - pfx[b];
        const int   r    = l * BB + b;
        const float st   = simt[r];
        const float coef = valid ? coef_s[b] : 0.f;
        const int   e    = events[b * LL + l + 1];   // l+1 <= len <= 2046

        int rs[8]; float ss[8];
#pragma unroll
        for (int j = 0; j < 8; ++j) {
            rs[j] = __shfl(r, j, 64);
            ss[j] = __shfl(st, j, 64);
        }

        // ---- staging with 3-deep load rotation + inline term 1 ----
        auto LD = [&](int rr_) -> RowT {
            const int base = rr_ * HH + lane * 4;
            RowT x;
            x.h = *(const float4*)(hidden + base);
            x.c = *(const float4*)(cell   + base);
            x.t = *(const float4*)(ctarg  + base);
            x.o = *(const float4*)(outp   + base);
            x.d = *(const float4*)(decay  + base);
            return x;
        };
        auto ST = [&](int j, const RowT& R, float stv) {
            float4 v;
            float cs, e2;
            cs = R.t.x + (R.c.x - R.t.x) * __expf(-R.d.x * stv); e2 = __expf(2.f * cs); v.x = R.o.x * ((e2 - 1.f) / (e2 + 1.f));
            cs = R.t.y + (R.c.y - R.t.y) * __expf(-R.d.y * stv); e2 = __expf(2.f * cs); v.y = R.o.y * ((e2 - 1.f) / (e2 + 1.f));
            cs = R.t.z + (R.c.z - R.t.z) * __expf(-R.d.z * stv); e2 = __expf(2.f * cs); v.z = R.o.z * ((e2 - 1.f) / (e2 + 1.f));
            cs = R.t.w + (R.c.w - R.t.w) * __expf(-R.d.w * stv); e2 = __expf(2.f * cs); v.w = R.o.w * ((e2 - 1.f) / (e2 + 1.f));
            *(uint2*)(Aw + ((j * 512 + lane * 8) ^ ((j & 7) << 4))) =
                make_uint2(f2bf(v.x) | (f2bf(v.y) << 16), f2bf(v.z) | (f2bf(v.w) << 16));

            // term 1 inline: su = dot(h_row_j, W[:, e_j]) with fp32 h, bf16 W
            const int ej = __shfl(e, j, 64);          // row j's event (uniform)
            const uint2 wc = *(const uint2*)(WTs + ((ej * 512 + lane * 8) ^ ((ej & 7) << 4)));
            float su = R.h.x * bflo(wc.x) + R.h.y * bfhi(wc.x)
                     + R.h.z * bflo(wc.y) + R.h.w * bfhi(wc.y);
#pragma unroll
            for (int mk = 1; mk < 64; mk <<= 1) su += __shfl_xor(su, mk, 64);
            const float be = __shfl((ej < 16) ? b_lo : b_hi, ej & 15, 64);
            if (lane == j && valid)                   // lane j owns row j
                acc -= __logf(softplus_f(su + be));
        };

        RowT buf[3];
        buf[0] = LD(rs[0]); buf[1] = LD(rs[1]); buf[2] = LD(rs[2]);
#pragma unroll
        for (int j = 0; j < 8; ++j) {
            ST(j, buf[j % 3], ss[j]);
            if (j + 3 < 8) buf[j % 3] = LD(rs[j + 3]);
        }

        // ---- MFMA: C rows 0-7 useful (lanes m>=8 re-read rows m-8) ----
        f32x4 C0 = {0.f,0.f,0.f,0.f}, C1 = {0.f,0.f,0.f,0.f};
        const int abase = (m & 7) * 512 + 16 * g;    // A-row (dup for m>=8)
        const int wbase = m * 512 + 16 * g;
        const int swza  = (m & 7) << 4;
#pragma unroll
        for (int c = 0; c < 8; ++c) {
            const short8 a  = *(const short8*)(Aw  + ((abase + 64 * c) ^ swza));
            const short8 w0 = *(const short8*)(WTs + ((wbase + 64 * c) ^ swza));
            const short8 w1 = *(const short8*)(WTs + ((wbase + 8192 + 64 * c) ^ swza));
            C0 = __builtin_amdgcn_mfma_f32_16x16x32_bf16(a, w0, C0, 0, 0, 0);
            C1 = __builtin_amdgcn_mfma_f32_16x16x32_bf16(a, w1, C1, 0, 0, 0);
        }

        // ---- term 2: C rows 0-7 (g<2), row = 4g+reg, col = m ----
        float sp[4];
#pragma unroll
        for (int reg = 0; reg < 4; ++reg)
            sp[reg] = softplus_f(C0[reg] + b_lo) + softplus_f(C1[reg] + b_hi);
#pragma unroll
        for (int mk = 1; mk <= 8; mk <<= 1) {
#pragma unroll
            for (int reg = 0; reg < 4; ++reg) sp[reg] += __shfl_xor(sp[reg], mk, 64);
        }
        float t2 = 0.f;
#pragma unroll
        for (int reg = 0; reg < 4; ++reg) {
            const float cf = __shfl(coef, 4 * g + reg, 64);  // coef of flat row 4g+reg
            t2 += cf * sp[reg];
        }
        if (m == 0 && g < 2) acc += t2;
    }

    // wave reduce + block reduce
#pragma unroll
    for (int mk = 1; mk < 64; mk <<= 1) acc += __shfl_xor(acc, mk, 64);
    if (lane == 0) wacc[q] = acc;
    __syncthreads();
    if (tid == 0) partial[blockIdx.x] = wacc[0] + wacc[1] + wacc[2] + wacc[3];
}

// Output: single float32 scalar.
__global__ __launch_bounds__(256) void nhll_finalize(
    const float* __restrict__ partial, float* __restrict__ out)
{
    __shared__ float red[4];
    float s = 0.f;
    for (int i = threadIdx.x; i < NB; i += 256) s += partial[i];
    for (int mk = 1; mk < 64; mk <<= 1) s += __shfl_xor(s, mk, 64);
    if ((threadIdx.x & 63) == 0) red[threadIdx.x >> 6] = s;
    __syncthreads();
    if (threadIdx.x == 0)
        out[0] = red[0] + red[1] + red[2] + red[3];
}

extern "C" void kernel_launch(void* const* d_in, const int* in_sizes, int n_in,
                              void* d_out, int out_size, void* d_ws, size_t ws_size,
                              hipStream_t stream) {
    const int*   events = (const int*)  d_in[0];   // event_seqs  [B,L] int32
    const int*   lens   = (const int*)  d_in[1];   // seqs_length [B]   int32
    const float* ttime  = (const float*)d_in[2];   // total_time  [B]
    const float* hidden = (const float*)d_in[3];   // [L,B,H]
    const float* cell   = (const float*)d_in[4];   // [L,B,H]
    const float* ctarg  = (const float*)d_in[5];   // [L,B,H]
    const float* outp   = (const float*)d_in[6];   // [L,B,H]
    const float* decay  = (const float*)d_in[7];   // [L,B,H]
    const float* simt   = (const float*)d_in[8];   // [L,B]
    const float* W      = (const float*)d_in[9];   // [H,K]
    const float* bias   = (const float*)d_in[10];  // [K]

    float* part = (float*)d_ws;                    // NB floats
    float* out  = (float*)d_out;

    nhll_main<<<NB, 256, 0, stream>>>(events, lens, ttime, hidden, cell, ctarg,
                                      outp, decay, simt, W, bias, part);
    nhll_finalize<<<1, 256, 0, stream>>>(part, out);
}

// Round 11
// 98.890 us; speedup vs baseline: 1.2078x; 1.2078x over previous
//
#include <hip/hip_runtime.h>

// Problem constants (match reference): B=64, L=2048, H=256, K=32
#define LL 2048
#define BB 64
#define HH 256
#define KK 32

#define NB  1024   // 4 blocks/CU exactly (LDS ~33.4 KB/block)
#define WPB 4      // waves per block

typedef __attribute__((ext_vector_type(8))) short  short8;   // 8 bf16 (4 VGPRs)
typedef __attribute__((ext_vector_type(4))) float  f32x4;

__device__ __forceinline__ float softplus_f(float x) {
    return x > 20.f ? x : __logf(1.f + __expf(x));
}
// round-to-nearest-even fp32 -> bf16
__device__ __forceinline__ unsigned f2bf(float x) {
    unsigned u = __builtin_bit_cast(unsigned, x);
    return (u + 0x7FFFu + ((u >> 16) & 1u)) >> 16;
}
__device__ __forceinline__ float bfhi(unsigned u) {   // high bf16 -> f32
    return __builtin_bit_cast(float, u & 0xFFFF0000u);
}
__device__ __forceinline__ float bflo(unsigned u) {   // low bf16 -> f32
    return __builtin_bit_cast(float, u << 16);
}

struct RowT { float4 h, c, t, o, d; };

// 8 flat rows per wave-tile. Per-wave LDS A-tile = 8 v-rows (4 KB, swizzled);
// hidden never touches LDS. Term 1: per-lane 4-FMA partials during staging,
// one batched 10-shuffle reduce-scatter after. 3-deep load rotation (R9).
// MFMA C rows 0-7 = v-dots (term 2); rows 8-15 are duplicates, masked.
__global__ __launch_bounds__(256, 3) void nhll_main(
    const int*   __restrict__ events,   // [B, L]
    const int*   __restrict__ lens,     // [B]
    const float* __restrict__ ttime,    // [B]
    const float* __restrict__ hidden,   // [L, B, H]
    const float* __restrict__ cell,     // [L, B, H]
    const float* __restrict__ ctarg,    // [L, B, H]
    const float* __restrict__ outp,     // [L, B, H]
    const float* __restrict__ decay,    // [L, B, H]
    const float* __restrict__ simt,     // [L, B]
    const float* __restrict__ W,        // [H, K]
    const float* __restrict__ bias,     // [K]
    float*       __restrict__ partial)  // [NB]
{
    __shared__ __align__(16) char  WTs[KK * HH * 2];       // 16 KB W^T bf16, swizzled
    __shared__ __align__(16) char  Als[WPB][8 * HH * 2];   // 4 KB per wave (v-rows)
    __shared__ int   pfx[BB + 1];
    __shared__ float coef_s[BB];
    __shared__ float bias_s[KK];
    __shared__ float wacc[WPB];

    const int tid  = threadIdx.x;
    const int lane = tid & 63;
    const int q    = tid >> 6;
    const int g    = lane >> 4;     // h-octet within K-chunk
    const int m    = lane & 15;     // C-col index

    // ---- one-time: W^T bf16 into LDS (row k, position h=tid, swizzled) ----
    {
        const float* wrow = &W[tid * KK];
#pragma unroll
        for (int k = 0; k < KK; ++k) {
            const int byte = (k * 512 + tid * 2) ^ ((k & 7) << 4);
            *(unsigned short*)(WTs + byte) = (unsigned short)f2bf(wrow[k]);
        }
    }
    if (tid < KK) bias_s[tid] = bias[tid];
    if (tid < BB) {                 // wave 0: scan lens -> prefix sums
        const int ln = lens[tid];
        coef_s[tid] = ttime[tid] / (float)ln;
        int s = ln;
#pragma unroll
        for (int mm = 1; mm < 64; mm <<= 1) {
            const int t = __shfl_up(s, mm, 64);
            if (lane >= mm) s += t;
        }
        pfx[tid + 1] = s;
        if (tid == 0) pfx[0] = 0;
    }
    __syncthreads();

    const float b_lo = bias[m];
    const float b_hi = bias[16 + m];
    const int   T      = pfx[BB];
    const int   ntiles = (T + 7) >> 3;
    // j index held by this lane after the reduce-scatter (bits 5,4,3)
    const int   jj = 4 * ((lane >> 5) & 1) + 2 * ((lane >> 4) & 1) + ((lane >> 3) & 1);
    char* Aw = Als[q];
    float acc = 0.f;

    for (int tile = blockIdx.x * WPB + q; tile < ntiles; tile += NB * WPB) {
        // ---- parallel metadata: lane j (j = lane&7) owns flat row tile*8+j ----
        int i = tile * 8 + (lane & 7);
        const int valid = (i < T) ? 1 : 0;
        if (!valid) i = T - 1;                    // clamp; masked below
        int lo = 0, hi = BB;
#pragma unroll
        for (int s = 0; s < 6; ++s) {
            const int mid = (lo + hi) >> 1;
            if (pfx[mid] <= i) lo = mid; else hi = mid;
        }
        const int   b    = lo;
        const int   l    = i - pfx[b];
        const int   r    = l * BB + b;
        const float st   = simt[r];
        const float coef = valid ? coef_s[b] : 0.f;
        const int   e    = events[b * LL + l + 1];   // l+1 <= len <= 2046

        int rs[8]; float ss[8];
#pragma unroll
        for (int j = 0; j < 8; ++j) {
            rs[j] = __shfl(r, j, 64);
            ss[j] = __shfl(st, j, 64);
        }

        // ---- staging: 3-deep load rotation; term-1 partials per lane ----
        float su[8];
        auto LD = [&](int rr_) -> RowT {
            const int base = rr_ * HH + lane * 4;
            RowT x;
            x.h = *(const float4*)(hidden + base);
            x.c = *(const float4*)(cell   + base);
            x.t = *(const float4*)(ctarg  + base);
            x.o = *(const float4*)(outp   + base);
            x.d = *(const float4*)(decay  + base);
            return x;
        };
        auto ST = [&](int j, const RowT& R, float stv) {
            float4 v;
            float cs, e2;
            cs = R.t.x + (R.c.x - R.t.x) * __expf(-R.d.x * stv); e2 = __expf(2.f * cs); v.x = R.o.x * ((e2 - 1.f) / (e2 + 1.f));
            cs = R.t.y + (R.c.y - R.t.y) * __expf(-R.d.y * stv); e2 = __expf(2.f * cs); v.y = R.o.y * ((e2 - 1.f) / (e2 + 1.f));
            cs = R.t.z + (R.c.z - R.t.z) * __expf(-R.d.z * stv); e2 = __expf(2.f * cs); v.z = R.o.z * ((e2 - 1.f) / (e2 + 1.f));
            cs = R.t.w + (R.c.w - R.t.w) * __expf(-R.d.w * stv); e2 = __expf(2.f * cs); v.w = R.o.w * ((e2 - 1.f) / (e2 + 1.f));
            *(uint2*)(Aw + ((j * 512 + lane * 8) ^ ((j & 7) << 4))) =
                make_uint2(f2bf(v.x) | (f2bf(v.y) << 16), f2bf(v.z) | (f2bf(v.w) << 16));
            // term-1 partial: dot of this lane's h-slice with W[:, e_j]
            const int ej = __shfl(e, j, 64);          // uniform (row j's event)
            const uint2 wc = *(const uint2*)(WTs + ((ej * 512 + lane * 8) ^ ((ej & 7) << 4)));
            su[j] = R.h.x * bflo(wc.x) + R.h.y * bfhi(wc.x)
                  + R.h.z * bflo(wc.y) + R.h.w * bfhi(wc.y);
        };

        RowT buf[3];
        buf[0] = LD(rs[0]); buf[1] = LD(rs[1]); buf[2] = LD(rs[2]);
#pragma unroll
        for (int j = 0; j < 8; ++j) {
            ST(j, buf[j % 3], ss[j]);
            if (j + 3 < 8) buf[j % 3] = LD(rs[j + 3]);
        }

        // ---- term 1 batched reduce: masks 32/16/8 scatter, 4/2/1 finish ----
#define RS_STEP(M, V)                                                         \
        {                                                                     \
            const bool hi_ = (lane & (M)) != 0;                               \
            _Pragma("unroll")                                                 \
            for (int ii = 0; ii < (V); ++ii) {                                \
                const float keep = hi_ ? su[ii + (V)] : su[ii];               \
                const float sent = hi_ ? su[ii] : su[ii + (V)];               \
                su[ii] = keep + __shfl_xor(sent, (M), 64);                    \
            }                                                                 \
        }
        RS_STEP(32, 4)
        RS_STEP(16, 2)
        RS_STEP(8, 1)
#undef RS_STEP
        su[0] += __shfl_xor(su[0], 4, 64);
        su[0] += __shfl_xor(su[0], 2, 64);
        su[0] += __shfl_xor(su[0], 1, 64);
        // every lane now holds S_{jj}; lanes 8j (lane&7==0) commit row jj
        {
            const int   ej = __shfl(e, jj, 64);
            const int   vl = __shfl(valid, jj, 64);
            const float be = bias_s[ej];
            if ((lane & 7) == 0 && vl)
                acc -= __logf(softplus_f(su[0] + be));
        }

        // ---- MFMA: C rows 0-7 useful (lanes m>=8 re-read rows m-8) ----
        f32x4 C0 = {0.f,0.f,0.f,0.f}, C1 = {0.f,0.f,0.f,0.f};
        const int abase = (m & 7) * 512 + 16 * g;    // A-row (dup for m>=8)
        const int wbase = m * 512 + 16 * g;
        const int swza  = (m & 7) << 4;
#pragma unroll
        for (int c = 0; c < 8; ++c) {
            const short8 a  = *(const short8*)(Aw  + ((abase + 64 * c) ^ swza));
            const short8 w0 = *(const short8*)(WTs + ((wbase + 64 * c) ^ swza));
            const short8 w1 = *(const short8*)(WTs + ((wbase + 8192 + 64 * c) ^ swza));
            C0 = __builtin_amdgcn_mfma_f32_16x16x32_bf16(a, w0, C0, 0, 0, 0);
            C1 = __builtin_amdgcn_mfma_f32_16x16x32_bf16(a, w1, C1, 0, 0, 0);
        }

        // ---- term 2: C rows 0-7 (g<2), row = 4g+reg, col = m ----
        float sp[4];
#pragma unroll
        for (int reg = 0; reg < 4; ++reg)
            sp[reg] = softplus_f(C0[reg] + b_lo) + softplus_f(C1[reg] + b_hi);
#pragma unroll
        for (int mk = 1; mk <= 8; mk <<= 1) {
#pragma unroll
            for (int reg = 0; reg < 4; ++reg) sp[reg] += __shfl_xor(sp[reg], mk, 64);
        }
        float t2 = 0.f;
#pragma unroll
        for (int reg = 0; reg < 4; ++reg) {
            const float cf = __shfl(coef, 4 * g + reg, 64);  // coef of flat row 4g+reg
            t2 += cf * sp[reg];
        }
        if (m == 0 && g < 2) acc += t2;
    }

    // wave reduce + block reduce
#pragma unroll
    for (int mk = 1; mk < 64; mk <<= 1) acc += __shfl_xor(acc, mk, 64);
    if (lane == 0) wacc[q] = acc;
    __syncthreads();
    if (tid == 0) partial[blockIdx.x] = wacc[0] + wacc[1] + wacc[2] + wacc[3];
}

// Output: single float32 scalar.
__global__ __launch_bounds__(256) void nhll_finalize(
    const float* __restrict__ partial, float* __restrict__ out)
{
    __shared__ float red[4];
    float s = 0.f;
    for (int i = threadIdx.x; i < NB; i += 256) s += partial[i];
    for (int mk = 1; mk < 64; mk <<= 1) s += __shfl_xor(s, mk, 64);
    if ((threadIdx.x & 63) == 0) red[threadIdx.x >> 6] = s;
    __syncthreads();
    if (threadIdx.x == 0)
        out[0] = red[0] + red[1] + red[2] + red[3];
}

extern "C" void kernel_launch(void* const* d_in, const int* in_sizes, int n_in,
                              void* d_out, int out_size, void* d_ws, size_t ws_size,
                              hipStream_t stream) {
    const int*   events = (const int*)  d_in[0];   // event_seqs  [B,L] int32
    const int*   lens   = (const int*)  d_in[1];   // seqs_length [B]   int32
    const float* ttime  = (const float*)d_in[2];   // total_time  [B]
    const float* hidden = (const float*)d_in[3];   // [L,B,H]
    const float* cell   = (const float*)d_in[4];   // [L,B,H]
    const float* ctarg  = (const float*)d_in[5];   // [L,B,H]
    const float* outp   = (const float*)d_in[6];   // [L,B,H]
    const float* decay  = (const float*)d_in[7];   // [L,B,H]
    const float* simt   = (const float*)d_in[8];   // [L,B]
    const float* W      = (const float*)d_in[9];   // [H,K]
    const float* bias   = (const float*)d_in[10];  // [K]

    float* part = (float*)d_ws;                    // NB floats
    float* out  = (float*)d_out;

    nhll_main<<<NB, 256, 0, stream>>>(events, lens, ttime, hidden, cell, ctarg,
                                      outp, decay, simt, W, bias, part);
    nhll_finalize<<<1, 256, 0, stream>>>(part, out);
}